// Round 9
// baseline (83.971 us; speedup 1.0000x reference)
//
#include <hip/hip_runtime.h>
#include <hip/hip_bf16.h>

#define MDIM 8192
#define KDIM 256
#define NTILES 2080  // 64*65/2 upper-triangle 128x128 tiles
#define NBLK 512     // 2 blocks per CU

typedef __attribute__((ext_vector_type(8))) short short8;
typedef __attribute__((ext_vector_type(4))) float f32x4;

__device__ __forceinline__ ushort bf16u(float f) {
    __hip_bfloat16 h = __float2bfloat16(f);
    return *reinterpret_cast<ushort*>(&h);
}

// async global->LDS, 16B per lane; LDS dest = wave-uniform base + lane*16.
__device__ __forceinline__ void async16(ushort* lds, const ushort* g) {
    __builtin_amdgcn_global_load_lds(
        (const __attribute__((address_space(1))) void*)g,
        (__attribute__((address_space(3))) void*)lds, 16, 0, 0);
}

// Kernel 1: each wave owns the row pair (i, i+4096): normalizes both rows to bf16,
// computes pos[i] = pos[i+4096] = 10*cos(x_i, x_p) in fp32, zeros row_sum.
__global__ __launch_bounds__(256) void knorm(const float* __restrict__ x,
                                             ushort* __restrict__ xn,
                                             float* __restrict__ row_sum,
                                             float* __restrict__ pos) {
    const int wave = threadIdx.x >> 6, lane = threadIdx.x & 63;
    const int i = blockIdx.x * 4 + wave;  // 0..4095
    const int p = i + 4096;
    const float4 a = *reinterpret_cast<const float4*>(x + (size_t)i * KDIM + lane * 4);
    const float4 b = *reinterpret_cast<const float4*>(x + (size_t)p * KDIM + lane * 4);
    float sa = a.x * a.x + a.y * a.y + a.z * a.z + a.w * a.w;
    float sb = b.x * b.x + b.y * b.y + b.z * b.z + b.w * b.w;
    float sab = a.x * b.x + a.y * b.y + a.z * b.z + a.w * b.w;
#pragma unroll
    for (int m = 1; m < 64; m <<= 1) {
        sa += __shfl_xor(sa, m, 64);
        sb += __shfl_xor(sb, m, 64);
        sab += __shfl_xor(sab, m, 64);
    }
    const float ia = 1.0f / fmaxf(sqrtf(sa), 1e-8f);
    const float ib = 1.0f / fmaxf(sqrtf(sb), 1e-8f);
    ushort4 oa, ob;
    oa.x = bf16u(a.x * ia); oa.y = bf16u(a.y * ia);
    oa.z = bf16u(a.z * ia); oa.w = bf16u(a.w * ia);
    ob.x = bf16u(b.x * ib); ob.y = bf16u(b.y * ib);
    ob.z = bf16u(b.z * ib); ob.w = bf16u(b.w * ib);
    *reinterpret_cast<ushort4*>(xn + (size_t)i * KDIM + lane * 4) = oa;
    *reinterpret_cast<ushort4*>(xn + (size_t)p * KDIM + lane * 4) = ob;
    if (lane == 0) {
        const float pv = 10.0f * sab * ia * ib;
        pos[i] = pv;
        pos[p] = pv;
    }
    if (threadIdx.x < 8) row_sum[blockIdx.x * 8 + threadIdx.x] = 0.0f;
}

// Kernel 2: B-stationary strip walk (R8 structure; R9 fixes the Breg spill).
// Tile (s, bi): A-rows [bi*128,+128) x B-cols [s*128,+128), bi <= s; strips s
// descending, bi ascending. 512 persistent blocks x 4-5 consecutive tiles.
// Per wave: Breg = 64 strip-cols x K256 in registers (128 VGPR, reloaded on
// strip change only); A = one 128x256 full-K LDS buffer staged per tile.
// K-loop: zero barriers/waitcnts. Per tile: B1 -> stageA(next) -> epilogue
// VALU hides DMA -> vmcnt(0)+B2.
// R9 change: __launch_bounds__(256, 1) so the allocator may use ~225 VGPRs
// (R8's (256,2) made it target 128 and spill Breg to scratch: VGPR_Count=128,
// FETCH_SIZE 66 MB of spill traffic, 70 us).
__global__ __launch_bounds__(256, 1) void ksim(const ushort* __restrict__ xn,
                                               float* __restrict__ row_sum) {
    __shared__ ushort As[128 * 256];  // 64 KB, single buffer, full K

    const int bid = blockIdx.x;
    const int blk = (bid & 7) * 64 + (bid >> 3);  // XCD swizzle (512%8==0, bijective)
    const int t0 = (blk * NTILES) >> 9;
    const int t1 = ((blk + 1) * NTILES) >> 9;

    // decode t0 -> (s, bi): u = NTILES - t0; s = smallest s with (s+1)(s+2)/2 >= u;
    // bi = (s+1)(s+2)/2 - u.
    const int u = NTILES - t0;
    int s = (int)(0.5f * (sqrtf(8.0f * (float)u + 1.0f) - 3.0f));
    if (s < 0) s = 0;
    while ((s + 1) * (s + 2) / 2 < u) ++s;
    while (s > 0 && s * (s + 1) / 2 >= u) --s;
    int bi = (s + 1) * (s + 2) / 2 - u;

    const int tid = threadIdx.x;
    const int wave = tid >> 6, lane = tid & 63;
    const int l16 = lane & 15, lhi = lane >> 4;
    const int wRow = (wave >> 1) * 64, wCol = (wave & 1) * 64;

    short8 Breg[32];  // [n*8+kc]: col wCol+n*16+l16, k in [kc*32+lhi*8, +8)
    auto loadB = [&](int ss) {
        const ushort* base = xn + (size_t)(ss * 128 + wCol + l16) * KDIM + lhi * 8;
#pragma unroll
        for (int n = 0; n < 4; ++n)
#pragma unroll
            for (int kc = 0; kc < 8; ++kc)
                Breg[n * 8 + kc] =
                    *reinterpret_cast<const short8*>(base + n * 16 * KDIM + kc * 32);
    };

    // stage tile nbi's A (128 rows x full K=256): 16 async16/wave, linear LDS dest,
    // XOR involution on the global source 16B-chunk index (rule 21).
    const int sub = lane >> 5;   // row parity within the lane sweep
    const int ch = lane & 31;    // 16B chunk within row (32 chunks = 512B row)
    auto stageA = [&](int nbi) {
#pragma unroll
        for (int q = 0; q < 16; ++q) {
            const int rr = (wave * 16 + q) * 2 + sub;
            const ushort* g = xn + (size_t)(nbi * 128 + rr) * KDIM + 8 * (ch ^ (rr & 7));
            async16(&As[(wave * 16 + q) * 512], g);
        }
    };

    f32x4 acc[4][4];
    float csum[4] = {0.f, 0.f, 0.f, 0.f};
#pragma unroll
    for (int m = 0; m < 4; ++m)
#pragma unroll
        for (int n = 0; n < 4; ++n) acc[m][n] = (f32x4){0.f, 0.f, 0.f, 0.f};

    loadB(s);
    stageA(bi);
    asm volatile("s_waitcnt vmcnt(0)\n\ts_barrier" ::: "memory");

    for (int tt = t0; tt < t1; ++tt) {
        // ---- K-loop: no sync inside; compiler pipelines ds_read vs MFMA ----
#pragma unroll
        for (int kc = 0; kc < 8; ++kc) {
            short8 a[4];
#pragma unroll
            for (int m = 0; m < 4; ++m)
                a[m] = *reinterpret_cast<const short8*>(
                    &As[(wRow + m * 16 + l16) * 256 + 8 * (((kc << 2) + lhi) ^ (l16 & 7))]);
#pragma unroll
            for (int m = 0; m < 4; ++m)
#pragma unroll
                for (int n = 0; n < 4; ++n)
                    acc[m][n] = __builtin_amdgcn_mfma_f32_16x16x32_bf16(
                        a[m], Breg[n * 8 + kc], acc[m][n], 0, 0, 0);
        }

        int nbi = bi + 1, ns = s;
        bool newstrip = false;
        if (nbi > s) { ns = s - 1; nbi = 0; newstrip = true; }
        const bool haveNext = (tt + 1 < t1);

        // B1: all waves' LDS reads consumed (lgkm-gated before their MFMAs issue)
        asm volatile("s_barrier" ::: "memory");
        if (haveNext) stageA(nbi);  // DMA lands under the epilogue below

        // ---- epilogue (regs/VALU/atomics only; no LDS) ----
        const bool diag = (bi == s);
        const int rB = bi * 128 + wRow;
#pragma unroll
        for (int m = 0; m < 4; ++m) {
            float psum[4] = {0.f, 0.f, 0.f, 0.f};
#pragma unroll
            for (int n = 0; n < 4; ++n)
#pragma unroll
                for (int j = 0; j < 4; ++j) {
                    float e = __expf(acc[m][n][j] * 10.0f);
                    if (diag && (wRow + m * 16 + lhi * 4 + j) == (wCol + n * 16 + l16))
                        e = 0.0f;
                    psum[j] += e;
                    if (!diag) csum[n] += e;  // diag tile: rows only (full tile present)
                    acc[m][n][j] = 0.0f;      // fused re-zero
                }
#pragma unroll
            for (int j = 0; j < 4; ++j) {
                float v = psum[j];
                v += __shfl_xor(v, 1, 16);
                v += __shfl_xor(v, 2, 16);
                v += __shfl_xor(v, 4, 16);
                v += __shfl_xor(v, 8, 16);
                if (l16 == 0) atomicAdd(&row_sum[rB + m * 16 + lhi * 4 + j], v);
            }
        }
        if (newstrip || !haveNext) {  // strip s done (for this block): flush col sums
#pragma unroll
            for (int n = 0; n < 4; ++n) {
                float v = csum[n];
                v += __shfl_xor(v, 16, 64);
                v += __shfl_xor(v, 32, 64);
                if (lhi == 0) atomicAdd(&row_sum[s * 128 + wCol + n * 16 + l16], v);
                csum[n] = 0.f;
            }
        }
        if (haveNext) {
            if (newstrip) loadB(ns);
            asm volatile("s_waitcnt vmcnt(0)\n\ts_barrier" ::: "memory");  // stage landed
        }
        bi = nbi;
        s = ns;
    }
}

// Kernel 3: loss = mean_i( log(row_sum[i]) - pos[i] )
__global__ __launch_bounds__(1024) void kfinal(const float* __restrict__ row_sum,
                                               const float* __restrict__ pos,
                                               float* __restrict__ out) {
    float acc = 0.f;
    for (int i = threadIdx.x; i < MDIM; i += 1024)
        acc += logf(row_sum[i]) - pos[i];
#pragma unroll
    for (int m = 1; m < 64; m <<= 1) acc += __shfl_xor(acc, m, 64);
    __shared__ float w[16];
    if ((threadIdx.x & 63) == 0) w[threadIdx.x >> 6] = acc;
    __syncthreads();
    if (threadIdx.x == 0) {
        float ssum = 0.f;
#pragma unroll
        for (int i = 0; i < 16; ++i) ssum += w[i];
        out[0] = ssum / (float)MDIM;
    }
}

extern "C" void kernel_launch(void* const* d_in, const int* in_sizes, int n_in,
                              void* d_out, int out_size, void* d_ws, size_t ws_size,
                              hipStream_t stream) {
    const float* x = (const float*)d_in[0];
    float* out = (float*)d_out;

    char* ws = (char*)d_ws;
    ushort* xn = (ushort*)ws;                                  // 8192*256*2 = 4 MB
    float* row_sum = (float*)(ws + (size_t)MDIM * KDIM * 2);   // 32 KB
    float* pos = row_sum + MDIM;                               // 32 KB

    knorm<<<MDIM / 8, 256, 0, stream>>>(x, xn, row_sum, pos);
    ksim<<<NBLK, 256, 0, stream>>>(xn, row_sum);
    kfinal<<<1, 1024, 0, stream>>>(row_sum, pos, out);
}

// Round 10
// 72.328 us; speedup vs baseline: 1.1610x; 1.1610x over previous
//
#include <hip/hip_runtime.h>
#include <hip/hip_bf16.h>

#define MDIM 8192
#define KDIM 256
#define NB 64        // 8192/128 tiles per dim
#define NTILES 2080  // NB*(NB+1)/2 upper-triangle tiles
#define NBLK 1024    // persistent blocks, 4 per CU (32 KB LDS, <=128 VGPR)

typedef __attribute__((ext_vector_type(8))) short short8;
typedef __attribute__((ext_vector_type(4))) float f32x4;

__device__ __forceinline__ ushort bf16u(float f) {
    __hip_bfloat16 h = __float2bfloat16(f);
    return *reinterpret_cast<ushort*>(&h);
}

// async global->LDS, 16B per lane; LDS dest = wave-uniform base + lane*16.
__device__ __forceinline__ void async16(ushort* lds, const ushort* g) {
    __builtin_amdgcn_global_load_lds(
        (const __attribute__((address_space(1))) void*)g,
        (__attribute__((address_space(3))) void*)lds, 16, 0, 0);
}

// Kernel 1: each wave owns the row pair (i, i+4096): normalizes both rows to bf16,
// computes pos[i] = pos[i+4096] = 10*cos(x_i, x_p) in fp32, zeros row_sum.
__global__ __launch_bounds__(256) void knorm(const float* __restrict__ x,
                                             ushort* __restrict__ xn,
                                             float* __restrict__ row_sum,
                                             float* __restrict__ pos) {
    const int wave = threadIdx.x >> 6, lane = threadIdx.x & 63;
    const int i = blockIdx.x * 4 + wave;  // 0..4095
    const int p = i + 4096;
    const float4 a = *reinterpret_cast<const float4*>(x + (size_t)i * KDIM + lane * 4);
    const float4 b = *reinterpret_cast<const float4*>(x + (size_t)p * KDIM + lane * 4);
    float sa = a.x * a.x + a.y * a.y + a.z * a.z + a.w * a.w;
    float sb = b.x * b.x + b.y * b.y + b.z * b.z + b.w * b.w;
    float sab = a.x * b.x + a.y * b.y + a.z * b.z + a.w * b.w;
#pragma unroll
    for (int m = 1; m < 64; m <<= 1) {
        sa += __shfl_xor(sa, m, 64);
        sb += __shfl_xor(sb, m, 64);
        sab += __shfl_xor(sab, m, 64);
    }
    const float ia = 1.0f / fmaxf(sqrtf(sa), 1e-8f);
    const float ib = 1.0f / fmaxf(sqrtf(sb), 1e-8f);
    ushort4 oa, ob;
    oa.x = bf16u(a.x * ia); oa.y = bf16u(a.y * ia);
    oa.z = bf16u(a.z * ia); oa.w = bf16u(a.w * ia);
    ob.x = bf16u(b.x * ib); ob.y = bf16u(b.y * ib);
    ob.z = bf16u(b.z * ib); ob.w = bf16u(b.w * ib);
    *reinterpret_cast<ushort4*>(xn + (size_t)i * KDIM + lane * 4) = oa;
    *reinterpret_cast<ushort4*>(xn + (size_t)p * KDIM + lane * 4) = ob;
    if (lane == 0) {
        const float pv = 10.0f * sab * ia * ib;
        pos[i] = pv;
        pos[p] = pv;
    }
    if (threadIdx.x < 8) row_sum[blockIdx.x * 8 + threadIdx.x] = 0.0f;
}

// Kernel 2: R4's proven flat pipeline (double-buffered global_load_lds chunks,
// counted vmcnt, per-step {vmcnt+bar / compute / bar / stage}), re-geometried
// for occupancy: BK=32 (LDS 32 KB -> 5 blocks/CU by LDS), grid 1024 (2-3 tiles
// per block, 4 blocks/CU co-resident = 16 waves/CU soaking the barrier/vmcnt
// waits). 8 steps/tile, 16 MFMA + 8 ds_read_b128 per wave per step, vmcnt(4).
// XOR involution for BK=32 (4 chunks/row): LDS[r][c] = G[r][c ^ ((r>>1)&3)];
// b128 reads spread 8 lanes per 4-bank group = the 1024B/128B minimum.
// Epilogue: prsum in regs across a bi-run (flush 16 atomics on bi change),
// 4 csum atomics per off-diag tile placed behind the stage loads in the vmcnt
// queue (vmcnt(4) tolerance = exactly the atomic tail -> no atomic stall).
__global__ __launch_bounds__(256, 4) void ksim(const ushort* __restrict__ xn,
                                               float* __restrict__ row_sum) {
    __shared__ ushort As[2][128 * 32];  // 8 KB each
    __shared__ ushort Bs[2][128 * 32];

    const int bid = blockIdx.x;
    const int blk = (bid & 7) * 128 + (bid >> 3);  // XCD swizzle (1024%8==0)
    const int t0 = (blk * 65) >> 5;                 // blk*2080/1024
    const int t1 = ((blk + 1) * 65) >> 5;
    const int S = 8 * (t1 - t0);                    // flat chunk-steps

    // decode t0 -> (bi, bj), row-major upper triangle (R4-proven)
    int bi = (int)((129.0f - sqrtf(16641.0f - 8.0f * (float)t0)) * 0.5f);
    while (NB * bi - bi * (bi - 1) / 2 > t0) --bi;
    while (NB * (bi + 1) - (bi + 1) * bi / 2 <= t0) ++bi;
    int bj = bi + (t0 - (NB * bi - bi * (bi - 1) / 2));

    const int t = threadIdx.x;
    const int wave = t >> 6, lane = t & 63;
    const int l16 = lane & 15, lhi = lane >> 4;
    const int wRow = (wave >> 1) * 64, wCol = (wave & 1) * 64;
    const bool wdiag = (wRow == wCol);

    // staging geometry (BK=32): async16 q covers 16 rows x 64B; lane ->
    // row (wave*2+q)*16 + (lane>>2), chunk lane&3; source chunk XOR (row>>1)&3
    // = (lane>>3)&3 (lane-only).
    const int srcc = 8 * ((lane & 3) ^ ((lane >> 3) & 3));
    const int rl = lane >> 2;
    // ds_read chunk for row r: lhi ^ ((r>>1)&3) with r&7 context = l16
    const int cx = 8 * (lhi ^ ((l16 >> 1) & 3));

    int sbi = bi, sbj = bj, sc = 0, sstep = 0;
    auto stage1 = [&]() {
        const int kk = sc * 32;
        const int buf = sstep & 1;
#pragma unroll
        for (int q = 0; q < 2; ++q) {
            const int rr = (wave * 2 + q) * 16 + rl;
            async16(&As[buf][(wave * 2 + q) * 512],
                    xn + (size_t)(sbi * 128 + rr) * KDIM + kk + srcc);
            async16(&Bs[buf][(wave * 2 + q) * 512],
                    xn + (size_t)(sbj * 128 + rr) * KDIM + kk + srcc);
        }
        ++sstep;
        if (++sc == 8) {
            sc = 0;
            if (++sbj == NB) { ++sbi; sbj = sbi; }
        }
    };

    f32x4 acc[4][4];
    float prsum[4][4];
#pragma unroll
    for (int a = 0; a < 4; ++a)
#pragma unroll
        for (int b = 0; b < 4; ++b) {
            acc[a][b] = (f32x4){0.f, 0.f, 0.f, 0.f};
            prsum[a][b] = 0.f;
        }

    auto compute = [&](int buf) {
        short8 a[4], bb[4];
#pragma unroll
        for (int f = 0; f < 4; ++f)
            a[f] = *reinterpret_cast<const short8*>(&As[buf][(wRow + f * 16 + l16) * 32 + cx]);
#pragma unroll
        for (int f = 0; f < 4; ++f)
            bb[f] = *reinterpret_cast<const short8*>(&Bs[buf][(wCol + f * 16 + l16) * 32 + cx]);
        __builtin_amdgcn_s_setprio(1);
#pragma unroll
        for (int fr = 0; fr < 4; ++fr)
#pragma unroll
            for (int fc = 0; fc < 4; ++fc)
                acc[fr][fc] = __builtin_amdgcn_mfma_f32_16x16x32_bf16(
                    a[fr], bb[fc], acc[fr][fc], 0, 0, 0);
        __builtin_amdgcn_s_setprio(0);
    };

    stage1();  // step 0
    stage1();  // step 1
    int cstep = 0;

    for (int tt = t0; tt < t1; ++tt) {
#pragma unroll
        for (int c = 0; c < 8; ++c, ++cstep) {
            if (cstep == S - 1)
                asm volatile("s_waitcnt vmcnt(0)\n\ts_barrier" ::: "memory");
            else
                asm volatile("s_waitcnt vmcnt(4)\n\ts_barrier" ::: "memory");
            compute(cstep & 1);
            asm volatile("s_barrier" ::: "memory");
            if (sstep < S) stage1();  // into the buffer just freed
        }

        // ---- tile epilogue (registers; 4 csum atomics ride the vmcnt tail) ----
        const bool diag = (bi == bj);
        if (diag) {
#pragma unroll
            for (int fr = 0; fr < 4; ++fr)
#pragma unroll
                for (int fc = 0; fc < 4; ++fc)
#pragma unroll
                    for (int j = 0; j < 4; ++j) {
                        float e = __expf(acc[fr][fc][j] * 10.0f);
                        if (wdiag && fr == fc && l16 == lhi * 4 + j) e = 0.0f;
                        prsum[fr][j] += e;
                        acc[fr][fc][j] = 0.0f;
                    }
        } else {
            float csum[4] = {0.f, 0.f, 0.f, 0.f};
#pragma unroll
            for (int fr = 0; fr < 4; ++fr)
#pragma unroll
                for (int fc = 0; fc < 4; ++fc)
#pragma unroll
                    for (int j = 0; j < 4; ++j) {
                        const float e = __expf(acc[fr][fc][j] * 10.0f);
                        prsum[fr][j] += e;
                        csum[fc] += e;
                        acc[fr][fc][j] = 0.0f;
                    }
#pragma unroll
            for (int fc = 0; fc < 4; ++fc) {
                float s = csum[fc];
                s += __shfl_xor(s, 16, 64);
                s += __shfl_xor(s, 32, 64);
                if (lhi == 0)
                    atomicAdd(&row_sum[bj * 128 + wCol + fc * 16 + l16], s);
            }
        }

        // advance; flush row partials when leaving a bi row (or at end)
        int nbi = bi, nbj = bj + 1;
        if (nbj == NB) { nbi = bi + 1; nbj = nbi; }
        if (tt == t1 - 1 || nbi != bi) {
#pragma unroll
            for (int fr = 0; fr < 4; ++fr)
#pragma unroll
                for (int j = 0; j < 4; ++j) {
                    float s = prsum[fr][j];
                    s += __shfl_xor(s, 1, 16);
                    s += __shfl_xor(s, 2, 16);
                    s += __shfl_xor(s, 4, 16);
                    s += __shfl_xor(s, 8, 16);
                    if (l16 == 0)
                        atomicAdd(&row_sum[bi * 128 + wRow + fr * 16 + lhi * 4 + j], s);
                    prsum[fr][j] = 0.f;
                }
        }
        bi = nbi;
        bj = nbj;
    }
}

// Kernel 3: loss = mean_i( log(row_sum[i]) - pos[i] )
__global__ __launch_bounds__(1024) void kfinal(const float* __restrict__ row_sum,
                                               const float* __restrict__ pos,
                                               float* __restrict__ out) {
    float acc = 0.f;
    for (int i = threadIdx.x; i < MDIM; i += 1024)
        acc += logf(row_sum[i]) - pos[i];
#pragma unroll
    for (int m = 1; m < 64; m <<= 1) acc += __shfl_xor(acc, m, 64);
    __shared__ float w[16];
    if ((threadIdx.x & 63) == 0) w[threadIdx.x >> 6] = acc;
    __syncthreads();
    if (threadIdx.x == 0) {
        float s = 0.f;
#pragma unroll
        for (int i = 0; i < 16; ++i) s += w[i];
        out[0] = s / (float)MDIM;
    }
}

extern "C" void kernel_launch(void* const* d_in, const int* in_sizes, int n_in,
                              void* d_out, int out_size, void* d_ws, size_t ws_size,
                              hipStream_t stream) {
    const float* x = (const float*)d_in[0];
    float* out = (float*)d_out;

    char* ws = (char*)d_ws;
    ushort* xn = (ushort*)ws;                                  // 8192*256*2 = 4 MB
    float* row_sum = (float*)(ws + (size_t)MDIM * KDIM * 2);   // 32 KB
    float* pos = row_sum + MDIM;                               // 32 KB

    knorm<<<MDIM / 8, 256, 0, stream>>>(x, xn, row_sum, pos);
    ksim<<<NBLK, 256, 0, stream>>>(xn, row_sum);
    kfinal<<<1, 1024, 0, stream>>>(row_sum, pos, out);
}